// Round 1
// baseline (2331.792 us; speedup 1.0000x reference)
//
#include <hip/hip_runtime.h>

// ---------------- workspace layout (float offsets) ----------------
// Liveness-overlaid; peak = 25,165,824 floats = 100,663,296 bytes.
#define WS_SEQ      0LL          // [3][16384][128]  (dead after xg_gru GEMM)
#define WS_XGGRU    6291456LL    // [6][16384][192]  (dead after gru_rec)
#define WS_X        0LL          // [3][16384][128]  (overwrites SEQ; dead after attention)
#define WS_TSTEP    18874368LL   // [16384][384]     (in old XGGRU region)
#define WS_S        6291456LL    // [64][256][256]   (scores, reused per pair)
#define WS_XGLSTM   0LL          // [2][16384][512]  (overwrites X/S)
#define WS_SF       16777216LL   // [16384][256]
#define WS_XGRGN    0LL          // [2][16384][384]
#define WS_OUT0     20971520LL   // [64][128]
#define WS_OUT1     20979712LL   // [64][128]

__device__ __forceinline__ float sigf(float x) { return 1.f / (1.f + __expf(-x)); }

// ---------------- generic fp32 GEMM: C = alpha*(A@W) [+bias] [+C] ------------
// A: M x K (optional row gather via idx), W: K x N (or N x K if wtrans)
#define BM 64
#define BN 64
#define BK 16

__global__ __launch_bounds__(256) void gemm_k(
    const float* __restrict__ A, long long a_z, int a_zdiv, int lda,
    const int* __restrict__ idx,
    const float* __restrict__ W, long long w_z, int wld, int wtrans,
    const float* __restrict__ bias, int bias_z,
    float* __restrict__ C, long long c_z, int ldc,
    int M, int N, int K, float alpha, int accum)
{
    int z = blockIdx.z;
    const float* Ab = A + (long long)(z / a_zdiv) * a_z;
    const float* Wb = W + (long long)z * w_z;
    const float* bb = bias ? bias + (long long)z * bias_z : nullptr;
    float* Cb = C + (long long)z * c_z;

    int m0 = blockIdx.y * BM;
    int n0 = blockIdx.x * BN;
    int tid = threadIdx.x;
    int tx = tid & 15, ty = tid >> 4;

    __shared__ __align__(16) float As[BK][BM + 4];
    __shared__ __align__(16) float Ws[BK][BN + 4];

    float acc[4][4];
#pragma unroll
    for (int i = 0; i < 4; ++i)
#pragma unroll
        for (int j = 0; j < 4; ++j) acc[i][j] = 0.f;

    for (int k0 = 0; k0 < K; k0 += BK) {
#pragma unroll
        for (int r = 0; r < 4; ++r) {
            int e = tid + r * 256;
            // A tile: k fastest across threads (coalesced 16-wide)
            int ak = e & 15, am = e >> 4;
            float av = 0.f;
            if (k0 + ak < K) {
                long long row = idx ? (long long)idx[m0 + am] : (long long)(m0 + am);
                av = Ab[row * (long long)lda + (k0 + ak)];
            }
            As[ak][am] = av;
            // W tile
            float wv = 0.f;
            if (!wtrans) {
                int wk = e >> 6, wn = e & 63;   // n fastest: coalesced
                if (k0 + wk < K) wv = Wb[(long long)(k0 + wk) * wld + (n0 + wn)];
                Ws[wk][wn] = wv;
            } else {
                int wn = e >> 4, wk = e & 15;   // k fastest: coalesced along K
                if (k0 + wk < K) wv = Wb[(long long)(n0 + wn) * wld + (k0 + wk)];
                Ws[wk][wn] = wv;
            }
        }
        __syncthreads();
#pragma unroll
        for (int k = 0; k < BK; ++k) {
            float4 av = *(const float4*)&As[k][ty * 4];
            float4 bv = *(const float4*)&Ws[k][tx * 4];
            acc[0][0] += av.x * bv.x; acc[0][1] += av.x * bv.y; acc[0][2] += av.x * bv.z; acc[0][3] += av.x * bv.w;
            acc[1][0] += av.y * bv.x; acc[1][1] += av.y * bv.y; acc[1][2] += av.y * bv.z; acc[1][3] += av.y * bv.w;
            acc[2][0] += av.z * bv.x; acc[2][1] += av.z * bv.y; acc[2][2] += av.z * bv.z; acc[2][3] += av.z * bv.w;
            acc[3][0] += av.w * bv.x; acc[3][1] += av.w * bv.y; acc[3][2] += av.w * bv.z; acc[3][3] += av.w * bv.w;
        }
        __syncthreads();
    }

#pragma unroll
    for (int i = 0; i < 4; ++i) {
        int gm = m0 + ty * 4 + i;
#pragma unroll
        for (int j = 0; j < 4; ++j) {
            int gn = n0 + tx * 4 + j;
            float v = alpha * acc[i][j];
            if (bb) v += bb[gn];
            float* cp = Cb + (long long)gm * ldc + gn;
            if (accum) v += *cp;
            *cp = v;
        }
    }
}

// ---------------- tstep init: tstep[:, m*128+c] = x[m][:, c] ----------------
__global__ __launch_bounds__(256) void copy_tstep_k(const float* __restrict__ x,
                                                    float* __restrict__ tstep)
{
    int o = blockIdx.x * 256 + threadIdx.x;      // 0 .. 6291456
    int c = o % 384;
    int row = o / 384;
    int m = c >> 7, cc = c & 127;
    tstep[o] = x[(long long)m * 2097152 + (long long)row * 128 + cc];
}

// ---------------- softmax over rows of 256 (one wave per row) ----------------
__global__ __launch_bounds__(256) void softmax_k(float* __restrict__ S)
{
    int wave = threadIdx.x >> 6, lane = threadIdx.x & 63;
    int row = blockIdx.x * 4 + wave;
    float* p = S + (long long)row * 256;
    float v[4];
    float mx = -1e30f;
#pragma unroll
    for (int i = 0; i < 4; ++i) { v[i] = p[lane + i * 64]; mx = fmaxf(mx, v[i]); }
#pragma unroll
    for (int off = 32; off > 0; off >>= 1) mx = fmaxf(mx, __shfl_xor(mx, off));
    float sum = 0.f;
#pragma unroll
    for (int i = 0; i < 4; ++i) { v[i] = __expf(v[i] - mx); sum += v[i]; }
#pragma unroll
    for (int off = 32; off > 0; off >>= 1) sum += __shfl_xor(sum, off);
    float inv = 1.f / sum;
#pragma unroll
    for (int i = 0; i < 4; ++i) p[lane + i * 64] = v[i] * inv;
}

// ---------------- GRU recurrence: one block per (b, stream) ------------------
// 192 threads, thread n owns gate-column n; Wh[:,n] (64 floats) in registers.
__global__ __launch_bounds__(192) void gru_rec_k(const float* __restrict__ xg,
                                                 const float* __restrict__ Wh,
                                                 const float* __restrict__ bh,
                                                 float* __restrict__ xout)
{
    int b = blockIdx.x, z = blockIdx.y;
    int m = z >> 1, d = z & 1;
    int n = threadIdx.x;
    const float* Whz = Wh + (long long)z * 64 * 192;
    float w[64];
#pragma unroll
    for (int i = 0; i < 64; ++i) w[i] = Whz[i * 192 + n];
    float bhn = bh[z * 192 + n];

    __shared__ __align__(16) float h[64];
    __shared__ float g[192];
    if (n < 64) h[n] = 0.f;
    __syncthreads();

    const float* xgb = xg + (long long)z * 3145728 + (long long)b * 256 * 192;
    float* xob = xout + (long long)m * 2097152 + (long long)b * 256 * 128 + d * 64;

    for (int t = 0; t < 256; ++t) {
        int tt = d ? 255 - t : t;
        const float* xr = xgb + tt * 192;
        float s0 = 0, s1 = 0, s2 = 0, s3 = 0;
#pragma unroll
        for (int i = 0; i < 64; i += 4) {
            float4 h4 = *(const float4*)&h[i];
            s0 += h4.x * w[i]; s1 += h4.y * w[i + 1];
            s2 += h4.z * w[i + 2]; s3 += h4.w * w[i + 3];
        }
        g[n] = (s0 + s1) + (s2 + s3) + bhn;
        __syncthreads();
        if (n < 64) {
            float hr = g[n], hz = g[64 + n], hn_ = g[128 + n];
            float r  = sigf(xr[n] + hr);
            float zz = sigf(xr[64 + n] + hz);
            float nn = tanhf(xr[128 + n] + r * hn_);
            float h2 = (1.f - zz) * nn + zz * h[n];
            h[n] = h2;                 // safe: all reads of old h happened pre-barrier
            xob[tt * 128 + n] = h2;
        }
        __syncthreads();
    }
}

// ---------------- LSTM recurrence: one block per (b, dir) --------------------
// 512 threads, thread n owns gate-column n; Wh[:,n] (128 floats) in registers.
__global__ __launch_bounds__(512) void lstm_rec_k(const float* __restrict__ xg,
                                                  const float* __restrict__ Wh,
                                                  const float* __restrict__ bh,
                                                  float* __restrict__ sf)
{
    int b = blockIdx.x, d = blockIdx.y;
    int n = threadIdx.x;
    const float* Whz = Wh + (long long)d * 128 * 512;
    float w[128];
#pragma unroll
    for (int i = 0; i < 128; ++i) w[i] = Whz[i * 512 + n];
    float bhn = bh[d * 512 + n];

    __shared__ __align__(16) float h[128];
    __shared__ float g[512];
    float c = 0.f;
    if (n < 128) h[n] = 0.f;
    __syncthreads();

    const float* xgb = xg + (long long)d * 8388608 + (long long)b * 256 * 512;
    float* sfb = sf + (long long)b * 256 * 256 + d * 128;

    for (int t = 0; t < 256; ++t) {
        int tt = d ? 255 - t : t;
        const float* xr = xgb + tt * 512;
        float s0 = 0, s1 = 0, s2 = 0, s3 = 0;
#pragma unroll
        for (int i = 0; i < 128; i += 4) {
            float4 h4 = *(const float4*)&h[i];
            s0 += h4.x * w[i]; s1 += h4.y * w[i + 1];
            s2 += h4.z * w[i + 2]; s3 += h4.w * w[i + 3];
        }
        g[n] = (s0 + s1) + (s2 + s3) + bhn + xr[n];
        __syncthreads();
        if (n < 128) {
            float iv = g[n], fv = g[128 + n], gv = g[256 + n], ov = g[384 + n];
            c = sigf(fv) * c + sigf(iv) * tanhf(gv);
            float h2 = sigf(ov) * tanhf(c);
            h[n] = h2;
            sfb[tt * 256 + n] = h2;
        }
        __syncthreads();
    }
}

// ---------------- RGN recurrence: one block per (b, dir), final h only -------
__global__ __launch_bounds__(384) void rgn_rec_k(const float* __restrict__ xg,
                                                 const float* __restrict__ Wh,
                                                 const float* __restrict__ state0,
                                                 const float* __restrict__ state1,
                                                 float* __restrict__ outbase)
{
    int b = blockIdx.x, d = blockIdx.y;
    int n = threadIdx.x;
    const float* Whz = Wh + (long long)d * 128 * 384;
    float w[128];
#pragma unroll
    for (int i = 0; i < 128; ++i) w[i] = Whz[i * 384 + n];

    __shared__ __align__(16) float h[128];
    __shared__ float g[384];
    const float* st = d ? state1 : state0;
    if (n < 128) h[n] = st[b * 128 + n];
    __syncthreads();

    const float* xgb = xg + (long long)d * 6291456 + (long long)b * 256 * 384;

    for (int t = 0; t < 256; ++t) {
        int tt = d ? 255 - t : t;
        const float* xr = xgb + tt * 384;
        float s0 = 0, s1 = 0, s2 = 0, s3 = 0;
#pragma unroll
        for (int i = 0; i < 128; i += 4) {
            float4 h4 = *(const float4*)&h[i];
            s0 += h4.x * w[i]; s1 += h4.y * w[i + 1];
            s2 += h4.z * w[i + 2]; s3 += h4.w * w[i + 3];
        }
        g[n] = (s0 + s1) + (s2 + s3);   // no hidden bias in RGN
        __syncthreads();
        if (n < 128) {
            float r  = sigf(xr[n] + g[n]);
            float zz = sigf(xr[128 + n] + g[128 + n]);
            float nn = tanhf(xr[256 + n] + r * g[256 + n]);
            h[n] = (1.f - zz) * nn + zz * h[n];
        }
        __syncthreads();
    }
    if (n < 128) outbase[(long long)d * 8192 + b * 128 + n] = h[n];
}

// ---------------- final FC: (out0+out1)@fc1 -> lrelu -> @fc2 -----------------
__global__ __launch_bounds__(256) void fc_k(const float* __restrict__ o01,
                                            const float* __restrict__ f1W,
                                            const float* __restrict__ f1b,
                                            const float* __restrict__ f2W,
                                            const float* __restrict__ f2b,
                                            float* __restrict__ out)
{
    __shared__ float s[8192];
    __shared__ float h1[2048];
    int tid = threadIdx.x;
    for (int e = tid; e < 8192; e += 256) s[e] = o01[e] + o01[8192 + e];
    __syncthreads();
    for (int o = tid; o < 2048; o += 256) {
        int b = o >> 5, q = o & 31;
        float acc = f1b[q];
        for (int k = 0; k < 128; ++k) acc += s[b * 128 + k] * f1W[k * 32 + q];
        h1[o] = acc >= 0.f ? acc : 0.01f * acc;   // jax leaky_relu slope 0.01
    }
    __syncthreads();
    if (tid < 64) {
        float acc = f2b[0];
        for (int q = 0; q < 32; ++q) acc += h1[tid * 32 + q] * f2W[q];
        out[tid] = acc;
    }
}

// ============================ launch =========================================
extern "C" void kernel_launch(void* const* d_in, const int* in_sizes, int n_in,
                              void* d_out, int out_size, void* d_ws, size_t ws_size,
                              hipStream_t stream)
{
    const int*   sent     = (const int*)  d_in[0];
    const float* acoustic = (const float*)d_in[1];
    const float* video    = (const float*)d_in[2];
    const float* state0   = (const float*)d_in[3];
    const float* state1   = (const float*)d_in[4];
    const float* emb      = (const float*)d_in[5];
    const float* plW = (const float*)d_in[6],  *plb = (const float*)d_in[7];
    const float* paW = (const float*)d_in[8],  *pab = (const float*)d_in[9];
    const float* pvW = (const float*)d_in[10], *pvb = (const float*)d_in[11];
    const float* gWi = (const float*)d_in[12], *gWh = (const float*)d_in[13];
    const float* gbi = (const float*)d_in[14], *gbh = (const float*)d_in[15];
    const float* lWi = (const float*)d_in[16], *lWh = (const float*)d_in[17];
    const float* lbi = (const float*)d_in[18], *lbh = (const float*)d_in[19];
    const float* rWx = (const float*)d_in[20], *rWh = (const float*)d_in[21];
    const float* rb  = (const float*)d_in[22];
    const float* f1W = (const float*)d_in[23], *f1b = (const float*)d_in[24];
    const float* f2W = (const float*)d_in[25], *f2b = (const float*)d_in[26];
    float* ws  = (float*)d_ws;
    float* out = (float*)d_out;

    dim3 blk(256);

    // 1-3: modality projections -> seq[3][16384][128]
    gemm_k<<<dim3(2, 256, 1), blk, 0, stream>>>(emb, 0, 1, 300, sent,
        plW, 0, 128, 0, plb, 0, ws + WS_SEQ, 0, 128, 16384, 128, 300, 1.f, 0);
    gemm_k<<<dim3(2, 256, 1), blk, 0, stream>>>(acoustic, 0, 1, 74, nullptr,
        paW, 0, 128, 0, pab, 0, ws + WS_SEQ + 2097152, 0, 128, 16384, 128, 74, 1.f, 0);
    gemm_k<<<dim3(2, 256, 1), blk, 0, stream>>>(video, 0, 1, 35, nullptr,
        pvW, 0, 128, 0, pvb, 0, ws + WS_SEQ + 4194304, 0, 128, 16384, 128, 35, 1.f, 0);

    // 4: GRU input projections, z = modality*2 + dir
    gemm_k<<<dim3(3, 256, 6), blk, 0, stream>>>(ws + WS_SEQ, 2097152, 2, 128, nullptr,
        gWi, 24576, 192, 0, gbi, 192, ws + WS_XGGRU, 3145728, 192, 16384, 192, 128, 1.f, 0);

    // 5: GRU recurrences -> x[3][16384][128]
    gru_rec_k<<<dim3(64, 6), dim3(192), 0, stream>>>(ws + WS_XGGRU, gWh, gbh, ws + WS_X);

    // 6: tstep = concat(x_l, x_a, x_v)
    copy_tstep_k<<<dim3(24576), blk, 0, stream>>>(ws + WS_X, ws + WS_TSTEP);

    // 7-9: six cross-attention pairs, accumulated into tstep slices
    const int qm[6] = {0, 0, 1, 1, 2, 2};
    const int km[6] = {1, 2, 0, 2, 0, 1};
    for (int p = 0; p < 6; ++p) {
        const float* xq = ws + WS_X + (long long)qm[p] * 2097152;
        const float* xk = ws + WS_X + (long long)km[p] * 2097152;
        // scores: S[b] = scale * q[b] @ kv[b]^T
        gemm_k<<<dim3(4, 4, 64), blk, 0, stream>>>(xq, 32768, 1, 128, nullptr,
            xk, 32768, 128, 1, nullptr, 0, ws + WS_S, 65536, 256,
            256, 256, 128, 0.08838834764831845f, 0);
        softmax_k<<<dim3(4096), blk, 0, stream>>>(ws + WS_S);
        // apply: tstep[:, qm*128 : qm*128+128] += P[b] @ kv[b]
        gemm_k<<<dim3(2, 4, 64), blk, 0, stream>>>(ws + WS_S, 65536, 1, 256, nullptr,
            xk, 32768, 128, 0, nullptr, 0, ws + WS_TSTEP + qm[p] * 128, 98304, 384,
            256, 128, 256, 1.f, 1);
    }

    // 10: LSTM input projections
    gemm_k<<<dim3(8, 256, 2), blk, 0, stream>>>(ws + WS_TSTEP, 0, 1, 384, nullptr,
        lWi, 196608, 512, 0, lbi, 512, ws + WS_XGLSTM, 8388608, 512, 16384, 512, 384, 1.f, 0);

    // 11: BiLSTM recurrences -> step_fusion[16384][256]
    lstm_rec_k<<<dim3(64, 2), dim3(512), 0, stream>>>(ws + WS_XGLSTM, lWh, lbh, ws + WS_SF);

    // 12: RGN input projections
    gemm_k<<<dim3(6, 256, 2), blk, 0, stream>>>(ws + WS_SF, 0, 1, 256, nullptr,
        rWx, 98304, 384, 0, rb, 384, ws + WS_XGRGN, 6291456, 384, 16384, 384, 256, 1.f, 0);

    // 13: RGN recurrences -> out0/out1 [64][128]
    rgn_rec_k<<<dim3(64, 2), dim3(384), 0, stream>>>(ws + WS_XGRGN, rWh, state0, state1,
                                                     ws + WS_OUT0);

    // 14: final FC -> d_out [64]
    fc_k<<<dim3(1), blk, 0, stream>>>(ws + WS_OUT0, f1W, f1b, f2W, f2b, out);
}

// Round 3
// 2165.003 us; speedup vs baseline: 1.0770x; 1.0770x over previous
//
#include <hip/hip_runtime.h>

// ---------------- workspace layout (float offsets) ----------------
#define WS_SEQ      0LL          // [3][16384][128]
#define WS_XGGRU    6291456LL    // [6][16384][192]
#define WS_X        0LL          // [3][16384][128]
#define WS_TSTEP    18874368LL   // [16384][384]
#define WS_S        6291456LL    // [64][256][256]
#define WS_XGLSTM   0LL          // [2][16384][512]
#define WS_SF       16777216LL   // [16384][256]
#define WS_XGRGN    0LL          // [2][16384][384]
#define WS_OUT0     20971520LL   // [2][64][128]

__device__ __forceinline__ float sigf(float x) { return 1.f / (1.f + __expf(-x)); }
// readlane: lane index MUST be wave-uniform (constant here, from unrolled loops)
__device__ __forceinline__ float rl(float v, int i) {
    return __int_as_float(__builtin_amdgcn_readlane(__float_as_int(v), i));
}

// ---------------- fp32 GEMM: 64x64 tile, 1 wave, 8x8 microtile ---------------
// C = alpha*(A@W) [+bias] [+C];  A: MxK (opt. row gather), W: KxN (NxK if wtrans)
__global__ __launch_bounds__(64) void gemm_k(
    const float* __restrict__ A, long long a_z, int a_zdiv, int lda,
    const int* __restrict__ idx,
    const float* __restrict__ W, long long w_z, int wld, int wtrans,
    const float* __restrict__ bias, int bias_z,
    float* __restrict__ C, long long c_z, int ldc,
    int M, int N, int K, float alpha, int accum)
{
    int z = blockIdx.z;
    const float* Ab = A + (long long)(z / a_zdiv) * a_z;
    const float* Wb = W + (long long)z * w_z;
    const float* bb = bias ? bias + (long long)z * bias_z : nullptr;
    float* Cb = C + (long long)z * c_z;

    int m0 = blockIdx.y * 64, n0 = blockIdx.x * 64;
    int t = threadIdx.x;
    int tx = t & 7, ty = t >> 3;

    __shared__ __align__(16) float As[16][68];
    __shared__ __align__(16) float Ws[16][68];

    float acc[8][8];
#pragma unroll
    for (int i = 0; i < 8; ++i)
#pragma unroll
        for (int j = 0; j < 8; ++j) acc[i][j] = 0.f;

    long long arow[4];
#pragma unroll
    for (int i = 0; i < 4; ++i) {
        int m = (t + i * 64) >> 2;
        arow[i] = idx ? (long long)idx[m0 + m] : (long long)(m0 + m);
    }
    const bool a_vec = ((lda & 3) == 0);

    for (int k0 = 0; k0 < K; k0 += 16) {
        // ---- stage A tile (64 m x 16 k) -> As[k][m] ----
#pragma unroll
        for (int i = 0; i < 4; ++i) {
            int j = t + i * 64;
            int m = j >> 2, kq = j & 3;
            int kk = k0 + kq * 4;
            const float* p = Ab + arow[i] * (long long)lda + kk;
            float4 v = {0.f, 0.f, 0.f, 0.f};
            if (a_vec && kk + 3 < K) {
                v = *(const float4*)p;
            } else {
                if (kk + 0 < K) v.x = p[0];
                if (kk + 1 < K) v.y = p[1];
                if (kk + 2 < K) v.z = p[2];
                if (kk + 3 < K) v.w = p[3];
            }
            As[kq * 4 + 0][m] = v.x; As[kq * 4 + 1][m] = v.y;
            As[kq * 4 + 2][m] = v.z; As[kq * 4 + 3][m] = v.w;
        }
        // ---- stage W tile (16 k x 64 n) -> Ws[k][n] ----
        if (!wtrans) {
#pragma unroll
            for (int i = 0; i < 4; ++i) {
                int j = t + i * 64;
                int k = j >> 4, nq = j & 15;
                float4 v = {0.f, 0.f, 0.f, 0.f};
                if (k0 + k < K)
                    v = *(const float4*)(Wb + (long long)(k0 + k) * wld + n0 + nq * 4);
                *(float4*)&Ws[k][nq * 4] = v;
            }
        } else {
#pragma unroll
            for (int i = 0; i < 4; ++i) {
                int j = t + i * 64;
                int n = j >> 2, kq = j & 3;
                int kk = k0 + kq * 4;
                const float* p = Wb + (long long)(n0 + n) * wld + kk;
                float4 v = {0.f, 0.f, 0.f, 0.f};
                if (kk + 3 < K) v = *(const float4*)p;
                else {
                    if (kk + 0 < K) v.x = p[0];
                    if (kk + 1 < K) v.y = p[1];
                    if (kk + 2 < K) v.z = p[2];
                    if (kk + 3 < K) v.w = p[3];
                }
                Ws[kq * 4 + 0][n] = v.x; Ws[kq * 4 + 1][n] = v.y;
                Ws[kq * 4 + 2][n] = v.z; Ws[kq * 4 + 3][n] = v.w;
            }
        }
        __syncthreads();
#pragma unroll
        for (int k = 0; k < 16; ++k) {
            float4 a0 = *(const float4*)&As[k][ty * 8];
            float4 a1 = *(const float4*)&As[k][ty * 8 + 4];
            float4 b0 = *(const float4*)&Ws[k][tx * 8];
            float4 b1 = *(const float4*)&Ws[k][tx * 8 + 4];
            float av[8] = {a0.x, a0.y, a0.z, a0.w, a1.x, a1.y, a1.z, a1.w};
            float bv[8] = {b0.x, b0.y, b0.z, b0.w, b1.x, b1.y, b1.z, b1.w};
#pragma unroll
            for (int i = 0; i < 8; ++i)
#pragma unroll
                for (int j = 0; j < 8; ++j)
                    acc[i][j] = fmaf(av[i], bv[j], acc[i][j]);
        }
        __syncthreads();
    }

#pragma unroll
    for (int i = 0; i < 8; ++i) {
        long long gm = m0 + ty * 8 + i;
#pragma unroll
        for (int jq = 0; jq < 2; ++jq) {
            float* cp = Cb + gm * ldc + n0 + tx * 8 + jq * 4;
            float4 v;
            v.x = alpha * acc[i][jq * 4 + 0]; v.y = alpha * acc[i][jq * 4 + 1];
            v.z = alpha * acc[i][jq * 4 + 2]; v.w = alpha * acc[i][jq * 4 + 3];
            if (bb) {
                const float* bp = bb + n0 + tx * 8 + jq * 4;
                v.x += bp[0]; v.y += bp[1]; v.z += bp[2]; v.w += bp[3];
            }
            if (accum) {
                float4 o = *(const float4*)cp;
                v.x += o.x; v.y += o.y; v.z += o.z; v.w += o.w;
            }
            *(float4*)cp = v;
        }
    }
}

// ---------------- tstep init ----------------
__global__ __launch_bounds__(256) void copy_tstep_k(const float* __restrict__ x,
                                                    float* __restrict__ tstep)
{
    int o = blockIdx.x * 256 + threadIdx.x;
    int c = o % 384;
    int row = o / 384;
    int m = c >> 7, cc = c & 127;
    tstep[o] = x[(long long)m * 2097152 + (long long)row * 128 + cc];
}

// ---------------- softmax over rows of 256 (one wave per row) ----------------
__global__ __launch_bounds__(256) void softmax_k(float* __restrict__ S)
{
    int wave = threadIdx.x >> 6, lane = threadIdx.x & 63;
    int row = blockIdx.x * 4 + wave;
    float* p = S + (long long)row * 256;
    float v[4];
    float mx = -1e30f;
#pragma unroll
    for (int i = 0; i < 4; ++i) { v[i] = p[lane + i * 64]; mx = fmaxf(mx, v[i]); }
#pragma unroll
    for (int off = 32; off > 0; off >>= 1) mx = fmaxf(mx, __shfl_xor(mx, off));
    float sum = 0.f;
#pragma unroll
    for (int i = 0; i < 4; ++i) { v[i] = __expf(v[i] - mx); sum += v[i]; }
#pragma unroll
    for (int off = 32; off > 0; off >>= 1) sum += __shfl_xor(sum, off);
    float inv = 1.f / sum;
#pragma unroll
    for (int i = 0; i < 4; ++i) p[lane + i * 64] = v[i] * inv;
}

// ---------------- GRU recurrence (readlane h-broadcast) ----------------------
__global__ __launch_bounds__(192) void gru_rec_k(const float* __restrict__ xg,
                                                 const float* __restrict__ Wh,
                                                 const float* __restrict__ bh,
                                                 float* __restrict__ xout)
{
    int b = blockIdx.x, z = blockIdx.y;
    int m = z >> 1, d = z & 1;
    int n = threadIdx.x, lane = n & 63;
    const float* Whz = Wh + (long long)z * 64 * 192;
    float w[64];
#pragma unroll
    for (int i = 0; i < 64; ++i) w[i] = Whz[i * 192 + n];
    float bhn = bh[z * 192 + n];

    __shared__ float hs[2][64];
    __shared__ float g[192];
    if (n < 64) hs[0][n] = 0.f;
    __syncthreads();

    const float* xgb = xg + (long long)z * 3145728 + (long long)b * 256 * 192;
    float* xob = xout + (long long)m * 2097152 + (long long)b * 256 * 128 + d * 64;

    for (int t = 0; t < 256; ++t) {
        int p = t & 1;
        int tt = d ? 255 - t : t;
        const float* xr = xgb + tt * 192;
        float xv = xr[n];
        float hA = hs[p][lane];                    // hA == h[lane]; for n<64, hA == h[n]
        float s0 = bhn, s1 = 0, s2 = 0, s3 = 0;
#pragma unroll
        for (int i = 0; i < 64; i += 4) {
            s0 = fmaf(rl(hA, i + 0), w[i + 0], s0);
            s1 = fmaf(rl(hA, i + 1), w[i + 1], s1);
            s2 = fmaf(rl(hA, i + 2), w[i + 2], s2);
            s3 = fmaf(rl(hA, i + 3), w[i + 3], s3);
        }
        g[n] = (s0 + s1) + (s2 + s3);
        __syncthreads();
        if (n < 64) {
            float r   = sigf(xv + g[n]);
            float zz  = sigf(xr[64 + n] + g[64 + n]);
            float nn  = tanhf(xr[128 + n] + r * g[128 + n]);
            float h2  = (1.f - zz) * nn + zz * hA;   // hA IS h[n] for this thread
            hs[1 - p][n] = h2;
            xob[tt * 128 + n] = h2;
        }
        __syncthreads();
    }
}

// ---------------- LSTM recurrence (readlane h-broadcast) ---------------------
__global__ __launch_bounds__(512) void lstm_rec_k(const float* __restrict__ xg,
                                                  const float* __restrict__ Wh,
                                                  const float* __restrict__ bh,
                                                  float* __restrict__ sf)
{
    int b = blockIdx.x, d = blockIdx.y;
    int n = threadIdx.x, lane = n & 63;
    const float* Whz = Wh + (long long)d * 128 * 512;
    float w[128];
#pragma unroll
    for (int i = 0; i < 128; ++i) w[i] = Whz[i * 512 + n];
    float bhn = bh[d * 512 + n];

    __shared__ float hs[2][128];
    __shared__ float g[512];
    float c = 0.f;
    if (n < 128) hs[0][n] = 0.f;
    __syncthreads();

    const float* xgb = xg + (long long)d * 8388608 + (long long)b * 256 * 512;
    float* sfb = sf + (long long)b * 256 * 256 + d * 128;

    for (int t = 0; t < 256; ++t) {
        int p = t & 1;
        int tt = d ? 255 - t : t;
        const float* xr = xgb + tt * 512;
        float xv = xr[n];
        float hA = hs[p][lane], hB = hs[p][64 + lane];
        float s0 = bhn + xv, s1 = 0, s2 = 0, s3 = 0;
#pragma unroll
        for (int i = 0; i < 64; i += 4) {
            s0 = fmaf(rl(hA, i + 0), w[i + 0], s0);
            s1 = fmaf(rl(hA, i + 1), w[i + 1], s1);
            s2 = fmaf(rl(hA, i + 2), w[i + 2], s2);
            s3 = fmaf(rl(hA, i + 3), w[i + 3], s3);
        }
#pragma unroll
        for (int i = 0; i < 64; i += 4) {
            s0 = fmaf(rl(hB, i + 0), w[64 + i + 0], s0);
            s1 = fmaf(rl(hB, i + 1), w[64 + i + 1], s1);
            s2 = fmaf(rl(hB, i + 2), w[64 + i + 2], s2);
            s3 = fmaf(rl(hB, i + 3), w[64 + i + 3], s3);
        }
        g[n] = (s0 + s1) + (s2 + s3);
        __syncthreads();
        if (n < 128) {
            float iv = g[n], fv = g[128 + n], gv = g[256 + n], ov = g[384 + n];
            c = sigf(fv) * c + sigf(iv) * tanhf(gv);
            float h2 = sigf(ov) * tanhf(c);
            hs[1 - p][n] = h2;
            sfb[tt * 256 + n] = h2;
        }
        __syncthreads();
    }
}

// ---------------- RGN recurrence (readlane h-broadcast) ----------------------
__global__ __launch_bounds__(384) void rgn_rec_k(const float* __restrict__ xg,
                                                 const float* __restrict__ Wh,
                                                 const float* __restrict__ state0,
                                                 const float* __restrict__ state1,
                                                 float* __restrict__ outbase)
{
    int b = blockIdx.x, d = blockIdx.y;
    int n = threadIdx.x, lane = n & 63;
    const float* Whz = Wh + (long long)d * 128 * 384;
    float w[128];
#pragma unroll
    for (int i = 0; i < 128; ++i) w[i] = Whz[i * 384 + n];

    __shared__ float hs[2][128];
    __shared__ float g[384];
    const float* st = d ? state1 : state0;
    if (n < 128) hs[0][n] = st[b * 128 + n];
    __syncthreads();

    const float* xgb = xg + (long long)d * 6291456 + (long long)b * 256 * 384;

    for (int t = 0; t < 256; ++t) {
        int p = t & 1;
        int tt = d ? 255 - t : t;
        const float* xr = xgb + tt * 384;
        float xv = xr[n];
        float hA = hs[p][lane], hB = hs[p][64 + lane];
        float s0 = 0, s1 = 0, s2 = 0, s3 = 0;
#pragma unroll
        for (int i = 0; i < 64; i += 4) {
            s0 = fmaf(rl(hA, i + 0), w[i + 0], s0);
            s1 = fmaf(rl(hA, i + 1), w[i + 1], s1);
            s2 = fmaf(rl(hA, i + 2), w[i + 2], s2);
            s3 = fmaf(rl(hA, i + 3), w[i + 3], s3);
        }
#pragma unroll
        for (int i = 0; i < 64; i += 4) {
            s0 = fmaf(rl(hB, i + 0), w[64 + i + 0], s0);
            s1 = fmaf(rl(hB, i + 1), w[64 + i + 1], s1);
            s2 = fmaf(rl(hB, i + 2), w[64 + i + 2], s2);
            s3 = fmaf(rl(hB, i + 3), w[64 + i + 3], s3);
        }
        g[n] = (s0 + s1) + (s2 + s3);
        __syncthreads();
        if (n < 128) {
            // h-old: wave 0 holds h[n] in hA, wave 1 holds h[n] in hB
            float hold = (n < 64) ? hA : hB;
            float r  = sigf(xv + g[n]);
            float zz = sigf(xr[128 + n] + g[128 + n]);
            float nn = tanhf(xr[256 + n] + r * g[256 + n]);
            hs[1 - p][n] = (1.f - zz) * nn + zz * hold;
        }
        __syncthreads();
    }
    if (n < 128) outbase[(long long)d * 8192 + b * 128 + n] = hs[0][n];
}

// ---------------- final FC ----------------
__global__ __launch_bounds__(256) void fc_k(const float* __restrict__ o01,
                                            const float* __restrict__ f1W,
                                            const float* __restrict__ f1b,
                                            const float* __restrict__ f2W,
                                            const float* __restrict__ f2b,
                                            float* __restrict__ out)
{
    __shared__ float s[8192];
    __shared__ float h1[2048];
    int tid = threadIdx.x;
    for (int e = tid; e < 8192; e += 256) s[e] = o01[e] + o01[8192 + e];
    __syncthreads();
    for (int o = tid; o < 2048; o += 256) {
        int b = o >> 5, q = o & 31;
        float acc = f1b[q];
        for (int k = 0; k < 128; ++k) acc += s[b * 128 + k] * f1W[k * 32 + q];
        h1[o] = acc >= 0.f ? acc : 0.01f * acc;
    }
    __syncthreads();
    if (tid < 64) {
        float acc = f2b[0];
        for (int q = 0; q < 32; ++q) acc += h1[tid * 32 + q] * f2W[q];
        out[tid] = acc;
    }
}

// ============================ launch =========================================
extern "C" void kernel_launch(void* const* d_in, const int* in_sizes, int n_in,
                              void* d_out, int out_size, void* d_ws, size_t ws_size,
                              hipStream_t stream)
{
    const int*   sent     = (const int*)  d_in[0];
    const float* acoustic = (const float*)d_in[1];
    const float* video    = (const float*)d_in[2];
    const float* state0   = (const float*)d_in[3];
    const float* state1   = (const float*)d_in[4];
    const float* emb      = (const float*)d_in[5];
    const float* plW = (const float*)d_in[6],  *plb = (const float*)d_in[7];
    const float* paW = (const float*)d_in[8],  *pab = (const float*)d_in[9];
    const float* pvW = (const float*)d_in[10], *pvb = (const float*)d_in[11];
    const float* gWi = (const float*)d_in[12], *gWh = (const float*)d_in[13];
    const float* gbi = (const float*)d_in[14], *gbh = (const float*)d_in[15];
    const float* lWi = (const float*)d_in[16], *lWh = (const float*)d_in[17];
    const float* lbi = (const float*)d_in[18], *lbh = (const float*)d_in[19];
    const float* rWx = (const float*)d_in[20], *rWh = (const float*)d_in[21];
    const float* rb  = (const float*)d_in[22];
    const float* f1W = (const float*)d_in[23], *f1b = (const float*)d_in[24];
    const float* f2W = (const float*)d_in[25], *f2b = (const float*)d_in[26];
    float* ws  = (float*)d_ws;
    float* out = (float*)d_out;

    dim3 blk(64);

    // modality projections -> seq[3][16384][128]
    gemm_k<<<dim3(2, 256, 1), blk, 0, stream>>>(emb, 0, 1, 300, sent,
        plW, 0, 128, 0, plb, 0, ws + WS_SEQ, 0, 128, 16384, 128, 300, 1.f, 0);
    gemm_k<<<dim3(2, 256, 1), blk, 0, stream>>>(acoustic, 0, 1, 74, nullptr,
        paW, 0, 128, 0, pab, 0, ws + WS_SEQ + 2097152, 0, 128, 16384, 128, 74, 1.f, 0);
    gemm_k<<<dim3(2, 256, 1), blk, 0, stream>>>(video, 0, 1, 35, nullptr,
        pvW, 0, 128, 0, pvb, 0, ws + WS_SEQ + 4194304, 0, 128, 16384, 128, 35, 1.f, 0);

    // GRU input projections, z = modality*2 + dir
    gemm_k<<<dim3(3, 256, 6), blk, 0, stream>>>(ws + WS_SEQ, 2097152, 2, 128, nullptr,
        gWi, 24576, 192, 0, gbi, 192, ws + WS_XGGRU, 3145728, 192, 16384, 192, 128, 1.f, 0);

    // GRU recurrences -> x[3][16384][128]
    gru_rec_k<<<dim3(64, 6), dim3(192), 0, stream>>>(ws + WS_XGGRU, gWh, gbh, ws + WS_X);

    // tstep = concat(x_l, x_a, x_v)
    copy_tstep_k<<<dim3(24576), dim3(256), 0, stream>>>(ws + WS_X, ws + WS_TSTEP);

    // six cross-attention pairs, accumulated into tstep slices
    const int qm[6] = {0, 0, 1, 1, 2, 2};
    const int km[6] = {1, 2, 0, 2, 0, 1};
    for (int p = 0; p < 6; ++p) {
        const float* xq = ws + WS_X + (long long)qm[p] * 2097152;
        const float* xk = ws + WS_X + (long long)km[p] * 2097152;
        gemm_k<<<dim3(4, 4, 64), blk, 0, stream>>>(xq, 32768, 1, 128, nullptr,
            xk, 32768, 128, 1, nullptr, 0, ws + WS_S, 65536, 256,
            256, 256, 128, 0.08838834764831845f, 0);
        softmax_k<<<dim3(4096), dim3(256), 0, stream>>>(ws + WS_S);
        gemm_k<<<dim3(2, 4, 64), blk, 0, stream>>>(ws + WS_S, 65536, 1, 256, nullptr,
            xk, 32768, 128, 0, nullptr, 0, ws + WS_TSTEP + qm[p] * 128, 98304, 384,
            256, 128, 256, 1.f, 1);
    }

    // LSTM input projections
    gemm_k<<<dim3(8, 256, 2), blk, 0, stream>>>(ws + WS_TSTEP, 0, 1, 384, nullptr,
        lWi, 196608, 512, 0, lbi, 512, ws + WS_XGLSTM, 8388608, 512, 16384, 512, 384, 1.f, 0);

    // BiLSTM recurrences -> step_fusion[16384][256]
    lstm_rec_k<<<dim3(64, 2), dim3(512), 0, stream>>>(ws + WS_XGLSTM, lWh, lbh, ws + WS_SF);

    // RGN input projections
    gemm_k<<<dim3(6, 256, 2), blk, 0, stream>>>(ws + WS_SF, 0, 1, 256, nullptr,
        rWx, 98304, 384, 0, rb, 384, ws + WS_XGRGN, 6291456, 384, 16384, 384, 256, 1.f, 0);

    // RGN recurrences -> out0/out1 [64][128]
    rgn_rec_k<<<dim3(64, 2), dim3(384), 0, stream>>>(ws + WS_XGRGN, rWh, state0, state1,
                                                     ws + WS_OUT0);

    // final FC -> d_out [64]
    fc_k<<<dim3(1), dim3(256), 0, stream>>>(ws + WS_OUT0, f1W, f1b, f2W, f2b, out);
}

// Round 4
// 2006.024 us; speedup vs baseline: 1.1624x; 1.0793x over previous
//
#include <hip/hip_runtime.h>

// ---------------- workspace layout (float offsets) ----------------
#define WS_SEQ      0LL          // [3][16384][128]
#define WS_XGGRU    6291456LL    // [6][16384][192]
#define WS_X        0LL          // [3][16384][128]
#define WS_TSTEP    18874368LL   // [16384][384]
#define WS_S        6291456LL    // [192][65536] scores (3 pairs x 64 batch)
#define WS_XGLSTM   0LL          // [2][16384][512]
#define WS_SF       16777216LL   // [16384][256]
#define WS_XGRGN    0LL          // [2][16384][384]
#define WS_OUT0     20971520LL   // [2][64][128]

__device__ __forceinline__ float sigf(float x) { return 1.f / (1.f + __expf(-x)); }
// readlane: lane index MUST be compile-time uniform (unrolled loops only)
__device__ __forceinline__ float rl(float v, int i) {
    return __int_as_float(__builtin_amdgcn_readlane(__float_as_int(v), i));
}

// ---------------- shared fp32 GEMM body: 64x64 tile, 1 wave, 8x8 micro -------
__device__ __forceinline__ void gemm_body(
    const float* __restrict__ Ab, int lda, const int* __restrict__ idx,
    const float* __restrict__ Wb, int wld, int wtrans,
    const float* __restrict__ bb,
    float* __restrict__ Cb, int ldc,
    int K, float alpha, int accum)
{
    int m0 = blockIdx.y * 64, n0 = blockIdx.x * 64;
    int t = threadIdx.x;
    int tx = t & 7, ty = t >> 3;

    __shared__ __align__(16) float As[16][68];
    __shared__ __align__(16) float Ws[16][68];

    float acc[8][8];
#pragma unroll
    for (int i = 0; i < 8; ++i)
#pragma unroll
        for (int j = 0; j < 8; ++j) acc[i][j] = 0.f;

    long long arow[4];
#pragma unroll
    for (int i = 0; i < 4; ++i) {
        int m = (t + i * 64) >> 2;
        arow[i] = idx ? (long long)idx[m0 + m] : (long long)(m0 + m);
    }
    const bool a_vec = ((lda & 3) == 0);

    for (int k0 = 0; k0 < K; k0 += 16) {
#pragma unroll
        for (int i = 0; i < 4; ++i) {
            int j = t + i * 64;
            int m = j >> 2, kq = j & 3;
            int kk = k0 + kq * 4;
            const float* p = Ab + arow[i] * (long long)lda + kk;
            float4 v = {0.f, 0.f, 0.f, 0.f};
            if (a_vec && kk + 3 < K) {
                v = *(const float4*)p;
            } else {
                if (kk + 0 < K) v.x = p[0];
                if (kk + 1 < K) v.y = p[1];
                if (kk + 2 < K) v.z = p[2];
                if (kk + 3 < K) v.w = p[3];
            }
            As[kq * 4 + 0][m] = v.x; As[kq * 4 + 1][m] = v.y;
            As[kq * 4 + 2][m] = v.z; As[kq * 4 + 3][m] = v.w;
        }
        if (!wtrans) {
#pragma unroll
            for (int i = 0; i < 4; ++i) {
                int j = t + i * 64;
                int k = j >> 4, nq = j & 15;
                float4 v = {0.f, 0.f, 0.f, 0.f};
                if (k0 + k < K)
                    v = *(const float4*)(Wb + (long long)(k0 + k) * wld + n0 + nq * 4);
                *(float4*)&Ws[k][nq * 4] = v;
            }
        } else {
#pragma unroll
            for (int i = 0; i < 4; ++i) {
                int j = t + i * 64;
                int n = j >> 2, kq = j & 3;
                int kk = k0 + kq * 4;
                const float* p = Wb + (long long)(n0 + n) * wld + kk;
                float4 v = {0.f, 0.f, 0.f, 0.f};
                if (kk + 3 < K) v = *(const float4*)p;
                else {
                    if (kk + 0 < K) v.x = p[0];
                    if (kk + 1 < K) v.y = p[1];
                    if (kk + 2 < K) v.z = p[2];
                    if (kk + 3 < K) v.w = p[3];
                }
                Ws[kq * 4 + 0][n] = v.x; Ws[kq * 4 + 1][n] = v.y;
                Ws[kq * 4 + 2][n] = v.z; Ws[kq * 4 + 3][n] = v.w;
            }
        }
        __syncthreads();
#pragma unroll
        for (int k = 0; k < 16; ++k) {
            float4 a0 = *(const float4*)&As[k][ty * 8];
            float4 a1 = *(const float4*)&As[k][ty * 8 + 4];
            float4 b0 = *(const float4*)&Ws[k][tx * 8];
            float4 b1 = *(const float4*)&Ws[k][tx * 8 + 4];
            float av[8] = {a0.x, a0.y, a0.z, a0.w, a1.x, a1.y, a1.z, a1.w};
            float bv[8] = {b0.x, b0.y, b0.z, b0.w, b1.x, b1.y, b1.z, b1.w};
#pragma unroll
            for (int i = 0; i < 8; ++i)
#pragma unroll
                for (int j = 0; j < 8; ++j)
                    acc[i][j] = fmaf(av[i], bv[j], acc[i][j]);
        }
        __syncthreads();
    }

#pragma unroll
    for (int i = 0; i < 8; ++i) {
        long long gm = m0 + ty * 8 + i;
#pragma unroll
        for (int jq = 0; jq < 2; ++jq) {
            float* cp = Cb + gm * ldc + n0 + tx * 8 + jq * 4;
            float4 v;
            v.x = alpha * acc[i][jq * 4 + 0]; v.y = alpha * acc[i][jq * 4 + 1];
            v.z = alpha * acc[i][jq * 4 + 2]; v.w = alpha * acc[i][jq * 4 + 3];
            if (bb) {
                const float* bp = bb + n0 + tx * 8 + jq * 4;
                v.x += bp[0]; v.y += bp[1]; v.z += bp[2]; v.w += bp[3];
            }
            if (accum) {
                float4 o = *(const float4*)cp;
                v.x += o.x; v.y += o.y; v.z += o.z; v.w += o.w;
            }
            *(float4*)cp = v;
        }
    }
}

// ---------------- generic GEMM launcher-kernel ----------------
__global__ __launch_bounds__(64) void gemm_k(
    const float* __restrict__ A, long long a_z, int a_zdiv, int lda,
    const int* __restrict__ idx,
    const float* __restrict__ W, long long w_z, int wld, int wtrans,
    const float* __restrict__ bias, int bias_z,
    float* __restrict__ C, long long c_z, int ldc,
    int K, float alpha, int accum)
{
    int z = blockIdx.z;
    gemm_body(A + (long long)(z / a_zdiv) * a_z, lda, idx,
              W + (long long)z * w_z, wld, wtrans,
              bias ? bias + (long long)z * bias_z : nullptr,
              C + (long long)z * c_z, ldc, K, alpha, accum);
}

// ---------------- batched attention score: S[z] = scale * q_b @ kv_b^T ------
__global__ __launch_bounds__(64) void att_score_k(
    const float* __restrict__ X, float* __restrict__ S,
    int q0, int q1, int q2, int k0, int k1, int k2)
{
    int z = blockIdx.z;
    int pair = z >> 6, b = z & 63;
    int qi = pair == 0 ? q0 : (pair == 1 ? q1 : q2);
    int ki = pair == 0 ? k0 : (pair == 1 ? k1 : k2);
    gemm_body(X + (long long)qi * 2097152 + (long long)b * 32768, 128, nullptr,
              X + (long long)ki * 2097152 + (long long)b * 32768, 128, 1,
              nullptr,
              S + (long long)z * 65536, 256, 128, 0.08838834764831845f, 0);
}

// ---------------- batched attention apply: tstep_slice += P_b @ kv_b --------
__global__ __launch_bounds__(64) void att_apply_k(
    const float* __restrict__ S, const float* __restrict__ X,
    float* __restrict__ tstep,
    int q0, int q1, int q2, int k0, int k1, int k2)
{
    int z = blockIdx.z;
    int pair = z >> 6, b = z & 63;
    int qi = pair == 0 ? q0 : (pair == 1 ? q1 : q2);
    int ki = pair == 0 ? k0 : (pair == 1 ? k1 : k2);
    gemm_body(S + (long long)z * 65536, 256, nullptr,
              X + (long long)ki * 2097152 + (long long)b * 32768, 128, 0,
              nullptr,
              tstep + (long long)qi * 128 + (long long)b * 98304, 384,
              256, 1.f, 1);
}

// ---------------- tstep init ----------------
__global__ __launch_bounds__(256) void copy_tstep_k(const float* __restrict__ x,
                                                    float* __restrict__ tstep)
{
    int o = blockIdx.x * 256 + threadIdx.x;
    int c = o % 384;
    int row = o / 384;
    int m = c >> 7, cc = c & 127;
    tstep[o] = x[(long long)m * 2097152 + (long long)row * 128 + cc];
}

// ---------------- softmax over rows of 256 (one wave per row) ----------------
__global__ __launch_bounds__(256) void softmax_k(float* __restrict__ S)
{
    int wave = threadIdx.x >> 6, lane = threadIdx.x & 63;
    int row = blockIdx.x * 4 + wave;
    float* p = S + (long long)row * 256;
    float v[4];
    float mx = -1e30f;
#pragma unroll
    for (int i = 0; i < 4; ++i) { v[i] = p[lane + i * 64]; mx = fmaxf(mx, v[i]); }
#pragma unroll
    for (int off = 32; off > 0; off >>= 1) mx = fmaxf(mx, __shfl_xor(mx, off));
    float sum = 0.f;
#pragma unroll
    for (int i = 0; i < 4; ++i) { v[i] = __expf(v[i] - mx); sum += v[i]; }
#pragma unroll
    for (int off = 32; off > 0; off >>= 1) sum += __shfl_xor(sum, off);
    float inv = 1.f / sum;
#pragma unroll
    for (int i = 0; i < 4; ++i) p[lane + i * 64] = v[i] * inv;
}

// ---------------- GRU recurrence: 1 wave, no LDS, no barriers ---------------
// lane n owns h[n] and all 3 gate columns (n, 64+n, 128+n): each rl feeds 3 FMAs
__global__ __launch_bounds__(64) void gru_rec_k(const float* __restrict__ xg,
                                                const float* __restrict__ Wh,
                                                const float* __restrict__ bh,
                                                float* __restrict__ xout)
{
    int b = blockIdx.x, z = blockIdx.y;
    int m = z >> 1, d = z & 1;
    int n = threadIdx.x;
    const float* Whz = Wh + (long long)z * 12288;
    float wr[64], wz[64], wn[64];
#pragma unroll
    for (int k = 0; k < 64; ++k) {
        wr[k] = Whz[k * 192 + n];
        wz[k] = Whz[k * 192 + 64 + n];
        wn[k] = Whz[k * 192 + 128 + n];
    }
    float br = bh[z * 192 + n], bz = bh[z * 192 + 64 + n], bn = bh[z * 192 + 128 + n];
    const float* xgb = xg + (long long)z * 3145728 + (long long)b * 49152;
    float* xob = xout + (long long)m * 2097152 + (long long)b * 32768 + d * 64;

    float h = 0.f;
    int tt0 = d ? 255 : 0;
    float x0 = xgb[tt0 * 192 + n], x1 = xgb[tt0 * 192 + 64 + n], x2 = xgb[tt0 * 192 + 128 + n];
#pragma unroll 1
    for (int t = 0; t < 256; ++t) {
        int tt = d ? 255 - t : t;
        float nx0 = 0.f, nx1 = 0.f, nx2 = 0.f;
        if (t < 255) {
            const float* xr = xgb + (d ? tt - 1 : tt + 1) * 192;
            nx0 = xr[n]; nx1 = xr[64 + n]; nx2 = xr[128 + n];
        }
        float sr0 = br, sr1 = 0.f, sz0 = bz, sz1 = 0.f, sn0 = bn, sn1 = 0.f;
#pragma unroll
        for (int k = 0; k < 64; k += 2) {
            float h0 = rl(h, k), h1 = rl(h, k + 1);
            sr0 = fmaf(h0, wr[k], sr0); sz0 = fmaf(h0, wz[k], sz0); sn0 = fmaf(h0, wn[k], sn0);
            sr1 = fmaf(h1, wr[k + 1], sr1); sz1 = fmaf(h1, wz[k + 1], sz1); sn1 = fmaf(h1, wn[k + 1], sn1);
        }
        float r  = sigf(x0 + sr0 + sr1);
        float zz = sigf(x1 + sz0 + sz1);
        float nn = tanhf(x2 + r * (sn0 + sn1));   // r multiplies ONLY the h-dot
        h = (1.f - zz) * nn + zz * h;
        xob[tt * 128 + n] = h;
        x0 = nx0; x1 = nx1; x2 = nx2;
    }
}

// ---------------- LSTM recurrence: 256 threads, 2 cols/thread ----------------
__global__ __launch_bounds__(256) void lstm_rec_k(const float* __restrict__ xg,
                                                  const float* __restrict__ Wh,
                                                  const float* __restrict__ bh,
                                                  float* __restrict__ sf)
{
    int b = blockIdx.x, d = blockIdx.y;
    int n = threadIdx.x, lane = n & 63;
    int c0 = n, c1 = n + 256;
    const float* Whz = Wh + (long long)d * 65536;
    float w0[128], w1[128];
#pragma unroll
    for (int k = 0; k < 128; ++k) { w0[k] = Whz[k * 512 + c0]; w1[k] = Whz[k * 512 + c1]; }
    float b0 = bh[d * 512 + c0], b1 = bh[d * 512 + c1];

    __shared__ float hs[2][128];
    __shared__ float g[512];
    float c = 0.f;
    if (n < 128) hs[0][n] = 0.f;
    __syncthreads();

    const float* xgb = xg + (long long)d * 8388608 + (long long)b * 131072;
    float* sfb = sf + (long long)b * 65536 + d * 128;

    int tt0 = d ? 255 : 0;
    float x0 = xgb[tt0 * 512 + c0], x1 = xgb[tt0 * 512 + c1];
#pragma unroll 1
    for (int t = 0; t < 256; ++t) {
        int p = t & 1;
        int tt = d ? 255 - t : t;
        float nx0 = 0.f, nx1 = 0.f;
        if (t < 255) {
            const float* xr = xgb + (d ? tt - 1 : tt + 1) * 512;
            nx0 = xr[c0]; nx1 = xr[c1];
        }
        float hA = hs[p][lane], hB = hs[p][64 + lane];
        float s0a = b0 + x0, s0b = 0.f, s1a = b1 + x1, s1b = 0.f;
#pragma unroll
        for (int k = 0; k < 64; k += 2) {
            float h0 = rl(hA, k), h1 = rl(hA, k + 1);
            s0a = fmaf(h0, w0[k], s0a);     s1a = fmaf(h0, w1[k], s1a);
            s0b = fmaf(h1, w0[k + 1], s0b); s1b = fmaf(h1, w1[k + 1], s1b);
        }
#pragma unroll
        for (int k = 0; k < 64; k += 2) {
            float h0 = rl(hB, k), h1 = rl(hB, k + 1);
            s0a = fmaf(h0, w0[64 + k], s0a);     s1a = fmaf(h0, w1[64 + k], s1a);
            s0b = fmaf(h1, w0[64 + k + 1], s0b); s1b = fmaf(h1, w1[64 + k + 1], s1b);
        }
        g[c0] = s0a + s0b;
        g[c1] = s1a + s1b;
        __syncthreads();
        if (n < 128) {
            float iv = g[n], fv = g[128 + n], gv = g[256 + n], ov = g[384 + n];
            c = sigf(fv) * c + sigf(iv) * tanhf(gv);
            float h2 = sigf(ov) * tanhf(c);
            hs[1 - p][n] = h2;
            sfb[tt * 256 + n] = h2;
        }
        __syncthreads();
        x0 = nx0; x1 = nx1;
    }
}

// ---------------- RGN recurrence: 192 threads, 2 cols/thread -----------------
__global__ __launch_bounds__(192) void rgn_rec_k(const float* __restrict__ xg,
                                                 const float* __restrict__ Wh,
                                                 const float* __restrict__ state0,
                                                 const float* __restrict__ state1,
                                                 float* __restrict__ outbase)
{
    int b = blockIdx.x, d = blockIdx.y;
    int n = threadIdx.x, lane = n & 63;
    int c0 = n, c1 = n + 192;
    const float* Whz = Wh + (long long)d * 49152;
    float w0[128], w1[128];
#pragma unroll
    for (int k = 0; k < 128; ++k) { w0[k] = Whz[k * 384 + c0]; w1[k] = Whz[k * 384 + c1]; }

    __shared__ float hs[2][128];
    __shared__ float g[384];
    __shared__ float xs[128];
    const float* st = d ? state1 : state0;
    if (n < 128) hs[0][n] = st[b * 128 + n];
    __syncthreads();

    const float* xgb = xg + (long long)d * 6291456 + (long long)b * 98304;

    int tt0 = d ? 255 : 0;
    float x0 = xgb[tt0 * 384 + c0], x1 = xgb[tt0 * 384 + c1];
#pragma unroll 1
    for (int t = 0; t < 256; ++t) {
        int p = t & 1;
        int tt = d ? 255 - t : t;
        float nx0 = 0.f, nx1 = 0.f;
        if (t < 255) {
            const float* xr = xgb + (d ? tt - 1 : tt + 1) * 384;
            nx0 = xr[c0]; nx1 = xr[c1];
        }
        float hA = hs[p][lane], hB = hs[p][64 + lane];
        float s0a = 0.f, s0b = 0.f, s1a = 0.f, s1b = 0.f;
#pragma unroll
        for (int k = 0; k < 64; k += 2) {
            float h0 = rl(hA, k), h1 = rl(hA, k + 1);
            s0a = fmaf(h0, w0[k], s0a);     s1a = fmaf(h0, w1[k], s1a);
            s0b = fmaf(h1, w0[k + 1], s0b); s1b = fmaf(h1, w1[k + 1], s1b);
        }
#pragma unroll
        for (int k = 0; k < 64; k += 2) {
            float h0 = rl(hB, k), h1 = rl(hB, k + 1);
            s0a = fmaf(h0, w0[64 + k], s0a);     s1a = fmaf(h0, w1[64 + k], s1a);
            s0b = fmaf(h1, w0[64 + k + 1], s0b); s1b = fmaf(h1, w1[64 + k + 1], s1b);
        }
        // r,z gates (cols <256): x folds into g. n-gate (cols >=256): keep x
        // separate (r multiplies only the h-dot) -> stash x in xs[].
        g[c0] = s0a + s0b + x0;
        if (n >= 64) {                     // c1 >= 256: n-gate column (wave-uniform)
            g[c1] = s1a + s1b;
            xs[c1 - 256] = x1;
        } else {
            g[c1] = s1a + s1b + x1;
        }
        __syncthreads();
        if (n < 128) {
            float hold = (n < 64) ? hA : hB;   // == h_old[n]
            float r  = sigf(g[n]);
            float zz = sigf(g[128 + n]);
            float nn = tanhf(xs[n] + r * g[256 + n]);
            hs[1 - p][n] = (1.f - zz) * nn + zz * hold;
        }
        __syncthreads();
        x0 = nx0; x1 = nx1;
    }
    if (n < 128) outbase[(long long)d * 8192 + b * 128 + n] = hs[0][n];
}

// ---------------- final FC ----------------
__global__ __launch_bounds__(256) void fc_k(const float* __restrict__ o01,
                                            const float* __restrict__ f1W,
                                            const float* __restrict__ f1b,
                                            const float* __restrict__ f2W,
                                            const float* __restrict__ f2b,
                                            float* __restrict__ out)
{
    __shared__ float s[8192];
    __shared__ float h1[2048];
    int tid = threadIdx.x;
    for (int e = tid; e < 8192; e += 256) s[e] = o01[e] + o01[8192 + e];
    __syncthreads();
    for (int o = tid; o < 2048; o += 256) {
        int b = o >> 5, q = o & 31;
        float acc = f1b[q];
        for (int k = 0; k < 128; ++k) acc += s[b * 128 + k] * f1W[k * 32 + q];
        h1[o] = acc >= 0.f ? acc : 0.01f * acc;
    }
    __syncthreads();
    if (tid < 64) {
        float acc = f2b[0];
        for (int q = 0; q < 32; ++q) acc += h1[tid * 32 + q] * f2W[q];
        out[tid] = acc;
    }
}

// ============================ launch =========================================
extern "C" void kernel_launch(void* const* d_in, const int* in_sizes, int n_in,
                              void* d_out, int out_size, void* d_ws, size_t ws_size,
                              hipStream_t stream)
{
    const int*   sent     = (const int*)  d_in[0];
    const float* acoustic = (const float*)d_in[1];
    const float* video    = (const float*)d_in[2];
    const float* state0   = (const float*)d_in[3];
    const float* state1   = (const float*)d_in[4];
    const float* emb      = (const float*)d_in[5];
    const float* plW = (const float*)d_in[6],  *plb = (const float*)d_in[7];
    const float* paW = (const float*)d_in[8],  *pab = (const float*)d_in[9];
    const float* pvW = (const float*)d_in[10], *pvb = (const float*)d_in[11];
    const float* gWi = (const float*)d_in[12], *gWh = (const float*)d_in[13];
    const float* gbi = (const float*)d_in[14], *gbh = (const float*)d_in[15];
    const float* lWi = (const float*)d_in[16], *lWh = (const float*)d_in[17];
    const float* lbi = (const float*)d_in[18], *lbh = (const float*)d_in[19];
    const float* rWx = (const float*)d_in[20], *rWh = (const float*)d_in[21];
    const float* rb  = (const float*)d_in[22];
    const float* f1W = (const float*)d_in[23], *f1b = (const float*)d_in[24];
    const float* f2W = (const float*)d_in[25], *f2b = (const float*)d_in[26];
    float* ws  = (float*)d_ws;
    float* out = (float*)d_out;

    dim3 blk(64);

    // modality projections -> seq[3][16384][128]
    gemm_k<<<dim3(2, 256, 1), blk, 0, stream>>>(emb, 0, 1, 300, sent,
        plW, 0, 128, 0, plb, 0, ws + WS_SEQ, 0, 128, 300, 1.f, 0);
    gemm_k<<<dim3(2, 256, 1), blk, 0, stream>>>(acoustic, 0, 1, 74, nullptr,
        paW, 0, 128, 0, pab, 0, ws + WS_SEQ + 2097152, 0, 128, 74, 1.f, 0);
    gemm_k<<<dim3(2, 256, 1), blk, 0, stream>>>(video, 0, 1, 35, nullptr,
        pvW, 0, 128, 0, pvb, 0, ws + WS_SEQ + 4194304, 0, 128, 35, 1.f, 0);

    // GRU input projections, z = modality*2 + dir
    gemm_k<<<dim3(3, 256, 6), blk, 0, stream>>>(ws + WS_SEQ, 2097152, 2, 128, nullptr,
        gWi, 24576, 192, 0, gbi, 192, ws + WS_XGGRU, 3145728, 192, 128, 1.f, 0);

    // GRU recurrences -> x[3][16384][128]
    gru_rec_k<<<dim3(64, 6), dim3(64), 0, stream>>>(ws + WS_XGGRU, gWh, gbh, ws + WS_X);

    // tstep = concat(x_l, x_a, x_v)
    copy_tstep_k<<<dim3(24576), dim3(256), 0, stream>>>(ws + WS_X, ws + WS_TSTEP);

    // attention: two race-free rounds of 3 pairs (distinct q-modality per round)
    // round 0: (q0,k1),(q1,k0),(q2,k0);  round 1: (q0,k2),(q1,k2),(q2,k1)
    att_score_k<<<dim3(4, 4, 192), blk, 0, stream>>>(ws + WS_X, ws + WS_S,
        0, 1, 2, 1, 0, 0);
    softmax_k<<<dim3(12288), dim3(256), 0, stream>>>(ws + WS_S);
    att_apply_k<<<dim3(2, 4, 192), blk, 0, stream>>>(ws + WS_S, ws + WS_X,
        ws + WS_TSTEP, 0, 1, 2, 1, 0, 0);
    att_score_k<<<dim3(4, 4, 192), blk, 0, stream>>>(ws + WS_X, ws + WS_S,
        0, 1, 2, 2, 2, 1);
    softmax_k<<<dim3(12288), dim3(256), 0, stream>>>(ws + WS_S);
    att_apply_k<<<dim3(2, 4, 192), blk, 0, stream>>>(ws + WS_S, ws + WS_X,
        ws + WS_TSTEP, 0, 1, 2, 2, 2, 1);

    // LSTM input projections
    gemm_k<<<dim3(8, 256, 2), blk, 0, stream>>>(ws + WS_TSTEP, 0, 1, 384, nullptr,
        lWi, 196608, 512, 0, lbi, 512, ws + WS_XGLSTM, 8388608, 512, 384, 1.f, 0);

    // BiLSTM recurrences -> step_fusion[16384][256]
    lstm_rec_k<<<dim3(64, 2), dim3(256), 0, stream>>>(ws + WS_XGLSTM, lWh, lbh, ws + WS_SF);

    // RGN input projections
    gemm_k<<<dim3(6, 256, 2), blk, 0, stream>>>(ws + WS_SF, 0, 1, 256, nullptr,
        rWx, 98304, 384, 0, rb, 384, ws + WS_XGRGN, 6291456, 384, 256, 1.f, 0);

    // RGN recurrences -> out0/out1 [64][128]
    rgn_rec_k<<<dim3(64, 2), dim3(192), 0, stream>>>(ws + WS_XGRGN, rWh, state0, state1,
                                                     ws + WS_OUT0);

    // final FC -> d_out [64]
    fc_k<<<dim3(1), dim3(256), 0, stream>>>(ws + WS_OUT0, f1W, f1b, f2W, f2b, out);
}